// Round 16
// baseline (110.921 us; speedup 1.0000x reference)
//
#include <hip/hip_runtime.h>
#include <math.h>

#define T_DIM 2048
#define N_B   2
#define C_DIM 1024
#define H_DIM 16
#define DH    64
#define M_DIM 4096
#define WIN   128

typedef _Float16 h8 __attribute__((ext_vector_type(8)));
typedef float    f4 __attribute__((ext_vector_type(4)));

#if __has_builtin(__builtin_amdgcn_exp2f)
#define EXP2(x) __builtin_amdgcn_exp2f(x)
#else
#define EXP2(x) __expf((x) * 0.693147180559945f)
#endif

// ---------------------------------------------------------------------------
// async global->LDS, 16B per lane (attn staging)
// ---------------------------------------------------------------------------
__device__ __forceinline__ void glds16(const _Float16* g, _Float16* l) {
    typedef const __attribute__((address_space(1))) unsigned int guint;
    typedef __attribute__((address_space(3))) unsigned int luint;
    __builtin_amdgcn_global_load_lds((guint*)g, (luint*)l, 16, 0, 0);
}

__device__ __forceinline__ h8 cvt8(const float4 a, const float4 b) {
    h8 o;
    o[0] = (_Float16)a.x; o[1] = (_Float16)a.y;
    o[2] = (_Float16)a.z; o[3] = (_Float16)a.w;
    o[4] = (_Float16)b.x; o[5] = (_Float16)b.y;
    o[6] = (_Float16)b.z; o[7] = (_Float16)b.w;
    return o;
}

// ---------------------------------------------------------------------------
// fp32 -> fp16 conversion prepass, WEIGHTS ONLY (4 x 1M elems = 24 MB traffic
// ~5us). Activations (48 MB fp32) stay fused into the GEMM staging --
// round 15 showed proj duration scales with per-step staged bytes, and the
// weight tile is 2/3 of them.
// ---------------------------------------------------------------------------
struct CvtA { const float* s; _Float16* d; };
struct Cvt4 { CvtA a[4]; };

__global__ __launch_bounds__(256) void cvt_w(Cvt4 c) {
    CvtA A = c.a[blockIdx.y];
    const int i = (blockIdx.x * 256 + threadIdx.x) * 8;
    const float4 v0 = *(const float4*)&A.s[i];
    const float4 v1 = *(const float4*)&A.s[i + 4];
    *(h8*)&A.d[i] = cvt8(v0, v1);
}

// ---------------------------------------------------------------------------
// Fused Q/K/V projection: A = fp32 activations (converted in-flight, 8KB/step)
// B = fp16 pre-converted weights (h8 pass-through, 8KB/step). Reg-staged
// depth-2 pipeline identical to round 15 (refcheck'd); only B dtype changed.
// 64x128 tile, 4 waves, acc[2][4]; coalesced epilogues.
// ---------------------------------------------------------------------------
struct QkvArgs {
    const float*    x[3];
    const _Float16* w[3];
    const float*    b[3];
    _Float16*       out[3];
};

__global__ __launch_bounds__(256) void proj_qkv(QkvArgs args) {
    const int z = blockIdx.z;
    const float* __restrict__ A     = args.x[z];
    const _Float16* __restrict__ B  = args.w[z];
    const float* __restrict__ bias  = args.b[z];
    _Float16* __restrict__ out      = args.out[z];

    __shared__ _Float16 Sm[2][6144];   // per buf: A 64x32 @0, B 128x32 @2048
    _Float16* smf = &Sm[0][0];

    const int tid  = threadIdx.x;
    const int lane = tid & 63;
    const int wave = tid >> 6;
    const int wr = wave >> 1, wc = wave & 1;
    const int l15 = lane & 15, hi = lane >> 4;
    const int m0 = blockIdx.x << 6;          // 64 rows
    const int o0 = blockIdx.y << 7;          // 128 cols

    const int rowA = tid >> 2, a4 = tid & 3;
    const int sw = ((a4 ^ ((rowA >> 1) & 3)) << 3);  // swizzled slot (elems)

    float4 ra0, ra1;
    h8 yb0, yb1;

    auto LOADR = [&](int k0) {
        const float* pa = &A[(size_t)(m0 + rowA) * C_DIM + k0 + a4 * 8];
        ra0 = *(const float4*)pa; ra1 = *(const float4*)(pa + 4);
        yb0 = *(const h8*)&B[(size_t)(o0 + rowA) * C_DIM + k0 + a4 * 8];
        yb1 = *(const h8*)&B[(size_t)(o0 + 64 + rowA) * C_DIM + k0 + a4 * 8];
    };
    auto WRITE = [&](int b) {
        *(h8*)&Sm[b][rowA * 32 + sw]               = cvt8(ra0, ra1);
        *(h8*)&Sm[b][2048 + rowA * 32 + sw]        = yb0;
        *(h8*)&Sm[b][2048 + (64 + rowA) * 32 + sw] = yb1;
    };

    f4 acc[2][4];
    const f4 z4 = {0.f, 0.f, 0.f, 0.f};
#pragma unroll
    for (int i = 0; i < 2; ++i)
#pragma unroll
        for (int j = 0; j < 4; ++j) acc[i][j] = z4;

    LOADR(0);
    WRITE(0);                    // compiler waits vmcnt on use of regs
    LOADR(32);
    asm volatile("s_waitcnt lgkmcnt(0)" ::: "memory");
    __builtin_amdgcn_s_barrier();
    __builtin_amdgcn_sched_barrier(0);

    int buf = 0;
    for (int k0 = 0; k0 < C_DIM; k0 += 32) {
        if (k0 + 32 < C_DIM) WRITE(buf ^ 1);      // tile t+1 (waits its loads)
        if (k0 + 64 < C_DIM) LOADR(k0 + 64);      // issue tile t+2

        h8 a[2], b[4];
#pragma unroll
        for (int mr = 0; mr < 2; ++mr) {
            const int R = wr * 32 + mr * 16 + l15;
            a[mr] = *(const h8*)&Sm[buf][R * 32 + ((hi ^ ((R >> 1) & 3)) << 3)];
        }
#pragma unroll
        for (int nf = 0; nf < 4; ++nf) {
            const int R = wc * 64 + nf * 16 + l15;
            b[nf] = *(const h8*)&Sm[buf][2048 + R * 32 + ((hi ^ ((R >> 1) & 3)) << 3)];
        }
#pragma unroll
        for (int mr = 0; mr < 2; ++mr)
#pragma unroll
            for (int nf = 0; nf < 4; ++nf)
                acc[mr][nf] = __builtin_amdgcn_mfma_f32_16x16x32_f16(
                    a[mr], b[nf], acc[mr][nf], 0, 0, 0);

        asm volatile("s_waitcnt lgkmcnt(0)" ::: "memory");  // publish writes
        __builtin_amdgcn_s_barrier();                        // vmcnt in flight
        __builtin_amdgcn_sched_barrier(0);
        buf ^= 1;
    }

    // -------- coalesced epilogue via LDS transpose scratch --------
    __syncthreads();
    const int hh = (o0 >> 6) + wc;
    if (z == 2) {
        // out (n,hh,d,t): scratch [n*64+d][24]; h8 stores of 8 t-values
        _Float16* ws = smf + wave * 3072;
#pragma unroll
        for (int nf = 0; nf < 4; ++nf) {
            const float bb = bias[o0 + wc * 64 + nf * 16 + l15];
            const int d = nf * 16 + l15;
#pragma unroll
            for (int mr = 0; mr < 2; ++mr)
#pragma unroll
                for (int reg = 0; reg < 4; ++reg) {
                    const int ml = mr * 16 + 4 * hi + reg;
                    ws[((ml & 1) * 64 + d) * 24 + (ml >> 1)] =
                        (_Float16)(acc[mr][nf][reg] + bb);
                }
        }
        const int tbase = (m0 + wr * 32) >> 1;
#pragma unroll
        for (int it = 0; it < 4; ++it) {
            const int c = lane + it * 64;    // 0..255
            const int rowi = c >> 1;         // n*64+d
            const int th = (c & 1) << 3;
            const h8 v = *(const h8*)&ws[rowi * 24 + th];
            const int n = rowi >> 6, d = rowi & 63;
            *(h8*)&out[((size_t)((n * 16 + hh) * 64 + d)) * T_DIM + tbase + th] = v;
        }
    } else {
        // out (n,hh,t,d): scratch [m 32][72]
        _Float16* ws = smf + wave * 2304;
#pragma unroll
        for (int nf = 0; nf < 4; ++nf) {
            const float bb = bias[o0 + wc * 64 + nf * 16 + l15];
#pragma unroll
            for (int mr = 0; mr < 2; ++mr)
#pragma unroll
                for (int reg = 0; reg < 4; ++reg)
                    ws[(mr * 16 + 4 * hi + reg) * 72 + nf * 16 + l15] =
                        (_Float16)(acc[mr][nf][reg] + bb);
        }
        const int t0 = (m0 + wr * 32) >> 1;
#pragma unroll
        for (int it = 0; it < 4; ++it) {
            const int c = lane + it * 64;    // 0..255
            const int nn = c >> 7;
            const int tq = (c >> 3) & 15;
            const int d8 = (c & 7) << 3;
            const int ml = (tq << 1) | nn;
            const h8 v = *(const h8*)&ws[ml * 72 + d8];
            *(h8*)&out[((size_t)(nn * 16 + hh) * T_DIM + t0 + tq) * DH + d8] = v;
        }
    }
}

// ---------------------------------------------------------------------------
// Output projection: A = attn output (fp16) and B = Wo fp16 (pre-converted),
// both staged as h8 pass-through. Sm[3] retained (epilogue needs 34816 B --
// round-14 lesson). fp32 float4 epilogue.
// ---------------------------------------------------------------------------
__global__ __launch_bounds__(256) void proj_o(
    const _Float16* __restrict__ A, const _Float16* __restrict__ B,
    const float* __restrict__ bias, float* __restrict__ out)
{
    __shared__ _Float16 Sm[3][6144];   // [0],[1] staging; [2] epilogue slack
    _Float16* smf = &Sm[0][0];

    const int tid  = threadIdx.x;
    const int lane = tid & 63;
    const int wave = tid >> 6;
    const int wr = wave >> 1, wc = wave & 1;
    const int l15 = lane & 15, hi = lane >> 4;
    const int m0 = blockIdx.x << 6;
    const int o0 = blockIdx.y << 7;

    const int rowA = tid >> 2, a4 = tid & 3;
    const int sw = ((a4 ^ ((rowA >> 1) & 3)) << 3);

    h8 ya, yb0, yb1;

    auto LOADR = [&](int k0) {
        ya  = *(const h8*)&A[(size_t)(m0 + rowA) * C_DIM + k0 + a4 * 8];
        yb0 = *(const h8*)&B[(size_t)(o0 + rowA) * C_DIM + k0 + a4 * 8];
        yb1 = *(const h8*)&B[(size_t)(o0 + 64 + rowA) * C_DIM + k0 + a4 * 8];
    };
    auto WRITE = [&](int b) {
        *(h8*)&Sm[b][rowA * 32 + sw]               = ya;
        *(h8*)&Sm[b][2048 + rowA * 32 + sw]        = yb0;
        *(h8*)&Sm[b][2048 + (64 + rowA) * 32 + sw] = yb1;
    };

    f4 acc[2][4];
    const f4 z4 = {0.f, 0.f, 0.f, 0.f};
#pragma unroll
    for (int i = 0; i < 2; ++i)
#pragma unroll
        for (int j = 0; j < 4; ++j) acc[i][j] = z4;

    LOADR(0);
    WRITE(0);
    LOADR(32);
    asm volatile("s_waitcnt lgkmcnt(0)" ::: "memory");
    __builtin_amdgcn_s_barrier();
    __builtin_amdgcn_sched_barrier(0);

    int buf = 0;
    for (int k0 = 0; k0 < C_DIM; k0 += 32) {
        if (k0 + 32 < C_DIM) WRITE(buf ^ 1);
        if (k0 + 64 < C_DIM) LOADR(k0 + 64);

        h8 a[2], b[4];
#pragma unroll
        for (int mr = 0; mr < 2; ++mr) {
            const int R = wr * 32 + mr * 16 + l15;
            a[mr] = *(const h8*)&Sm[buf][R * 32 + ((hi ^ ((R >> 1) & 3)) << 3)];
        }
#pragma unroll
        for (int nf = 0; nf < 4; ++nf) {
            const int R = wc * 64 + nf * 16 + l15;
            b[nf] = *(const h8*)&Sm[buf][2048 + R * 32 + ((hi ^ ((R >> 1) & 3)) << 3)];
        }
#pragma unroll
        for (int mr = 0; mr < 2; ++mr)
#pragma unroll
            for (int nf = 0; nf < 4; ++nf)
                acc[mr][nf] = __builtin_amdgcn_mfma_f32_16x16x32_f16(
                    a[mr], b[nf], acc[mr][nf], 0, 0, 0);

        asm volatile("s_waitcnt lgkmcnt(0)" ::: "memory");
        __builtin_amdgcn_s_barrier();
        __builtin_amdgcn_sched_barrier(0);
        buf ^= 1;
    }

    // coalesced fp32 epilogue: scratch [m 32][68] floats, float4 stores
    __syncthreads();
    float* wsf = (float*)smf + wave * 2176;
#pragma unroll
    for (int nf = 0; nf < 4; ++nf) {
        const float bb = bias[o0 + wc * 64 + nf * 16 + l15];
#pragma unroll
        for (int mr = 0; mr < 2; ++mr)
#pragma unroll
            for (int reg = 0; reg < 4; ++reg)
                wsf[(mr * 16 + 4 * hi + reg) * 68 + nf * 16 + l15] =
                    acc[mr][nf][reg] + bb;
    }
#pragma unroll
    for (int it = 0; it < 8; ++it) {
        const int c = lane + it * 64;        // 0..511
        const int ml = c >> 4;
        const int o4 = (c & 15) << 2;
        const f4 v = *(const f4*)&wsf[ml * 68 + o4];
        *(f4*)&out[(size_t)(m0 + wr * 32 + ml) * C_DIM + o0 + wc * 64 + o4] = v;
    }
}

// ---------------------------------------------------------------------------
// Flash attention v7 (unchanged): 4-wave blocks, 128 q-rows, LDS-staged
// swizzled K/V^T, double-buffered, kept-tile walker, defer-max.
// ---------------------------------------------------------------------------
__global__ __launch_bounds__(256, 2) void attn_v7(
    const _Float16* __restrict__ QH, const _Float16* __restrict__ KH,
    const _Float16* __restrict__ VT, const int* __restrict__ key_length,
    _Float16* __restrict__ Y)
{
    __shared__ _Float16 Ks[2][64 * 64];     // [key][d], swizzled
    __shared__ _Float16 Vs[2][64 * 64];     // [d][key], swizzled
    __shared__ _Float16 Ps[4][32 * 72];     // per-wave P routing

    const int nh = blockIdx.x;
    const int n  = nh >> 4;
    const int h  = nh & 15;
    const int qb = blockIdx.y << 7;          // 128 q-rows per block
    const int kl = key_length[n];
    const int tid  = threadIdx.x;
    const int wave = tid >> 6;
    const int lane = tid & 63;
    const int l15 = lane & 15, hi = lane >> 4;
    const int qw = qb + wave * 32;           // this wave's 32 rows
    const int swz = l15 & 7;                 // read-side XOR key

    const size_t hb = (size_t)nh * T_DIM * DH;
    const _Float16* Qb = QH + hb;
    const _Float16* Kb = KH + hb;
    const _Float16* Vb = VT + hb;            // [d][t] within this head

    // block-level kept-tile walker: prefix [0,klc) union band [blo,bhi]
    const int klc0 = ((kl + 63) >> 6) << 6;
    const int klc  = (klc0 < T_DIM) ? klc0 : T_DIM;
    const int blo  = (qb >= WIN) ? ((qb - WIN) & ~63) : 0;
    int bhi = ((qb + 127 + WIN) >> 6) << 6;
    if (bhi > T_DIM - 64) bhi = T_DIM - 64;
    auto nxt = [&](int k0) -> int {
        k0 += 64;
        if (k0 < klc) return k0;
        if (k0 < blo) k0 = blo;
        return (k0 <= bhi) ? k0 : -1;
    };

    auto STAGE = [&](int b, int k0) {
#pragma unroll
        for (int c = 0; c < 2; ++c) {
            const int slot = wave * 128 + c * 64 + lane;   // 16B slot in tile
            const int r = slot >> 3, c16 = slot & 7;
            const int sc = (c16 ^ (r & 7)) << 3;           // element offset
            glds16(&Kb[(size_t)(k0 + r) * DH + sc], &Ks[b][slot << 3]);
        }
#pragma unroll
        for (int c = 0; c < 2; ++c) {
            const int slot = wave * 128 + c * 64 + lane;
            const int r = slot >> 3, c16 = slot & 7;
            const int sc = (c16 ^ (r & 7)) << 3;
            glds16(&Vb[(size_t)r * T_DIM + k0 + sc], &Vs[b][slot << 3]);
        }
    };

    // Q A-fragments
    h8 qa[2][2];
#pragma unroll
    for (int mr = 0; mr < 2; ++mr)
#pragma unroll
        for (int ks = 0; ks < 2; ++ks)
            qa[mr][ks] = *(const h8*)&Qb[(size_t)(qw + mr * 16 + l15) * DH + ks * 32 + hi * 8];

    f4 O[2][4];
    const f4 z4 = {0.f, 0.f, 0.f, 0.f};
#pragma unroll
    for (int mr = 0; mr < 2; ++mr)
#pragma unroll
        for (int df = 0; df < 4; ++df) O[mr][df] = z4;
    float m_i[2][4], lp[2][4];
#pragma unroll
    for (int mr = 0; mr < 2; ++mr)
#pragma unroll
        for (int r = 0; r < 4; ++r) { m_i[mr][r] = -1e30f; lp[mr][r] = 0.f; }

    const float SC = 0.18033688f;            // (1/sqrt(64)) * log2(e)

    auto TILE = [&](int b, int k0) {
        // K fragments from swizzled LDS
        h8 kb[2][4];
#pragma unroll
        for (int ks = 0; ks < 2; ++ks)
#pragma unroll
            for (int cf = 0; cf < 4; ++cf)
                kb[ks][cf] = *(const h8*)&Ks[b][(cf * 16 + l15) * 64 +
                                                (((ks * 4 + hi) ^ swz) << 3)];

        // S = Q K^T
        f4 sacc[2][4];
#pragma unroll
        for (int mr = 0; mr < 2; ++mr)
#pragma unroll
            for (int cf = 0; cf < 4; ++cf) sacc[mr][cf] = z4;
#pragma unroll
        for (int ks = 0; ks < 2; ++ks)
#pragma unroll
            for (int mr = 0; mr < 2; ++mr)
#pragma unroll
                for (int cf = 0; cf < 4; ++cf)
                    sacc[mr][cf] = __builtin_amdgcn_mfma_f32_16x16x32_f16(
                        qa[mr][ks], kb[ks][cf], sacc[mr][cf], 0, 0, 0);

        // V fragments issued now; LDS latency hides under softmax
        h8 vb[2][4];
#pragma unroll
        for (int ks = 0; ks < 2; ++ks)
#pragma unroll
            for (int df = 0; df < 4; ++df)
                vb[ks][df] = *(const h8*)&Vs[b][(df * 16 + l15) * 64 +
                                                (((ks * 4 + hi) ^ swz) << 3)];

        const bool full = (k0 + 63 < kl) ||
                          (k0 >= qw + 31 - WIN && k0 + 63 <= qw + WIN);

        // scale + mask in place
#pragma unroll
        for (int mr = 0; mr < 2; ++mr) {
            if (full) {
#pragma unroll
                for (int cf = 0; cf < 4; ++cf)
#pragma unroll
                    for (int reg = 0; reg < 4; ++reg)
                        sacc[mr][cf][reg] *= SC;
            } else {
#pragma unroll
                for (int cf = 0; cf < 4; ++cf)
#pragma unroll
                    for (int reg = 0; reg < 4; ++reg) {
                        const int i = qw + mr * 16 + 4 * hi + reg;
                        const int j = k0 + cf * 16 + l15;
                        const int dd = i - j;
                        const bool ok = (dd <= WIN && dd >= -WIN) || (j < kl);
                        sacc[mr][cf][reg] = ok ? sacc[mr][cf][reg] * SC : -1e9f;
                    }
            }
        }

        // defer-max: reduce + rescale only when some lane exceeds m_i
        float lm[2][4];
        bool need = false;
#pragma unroll
        for (int mr = 0; mr < 2; ++mr)
#pragma unroll
            for (int reg = 0; reg < 4; ++reg) {
                lm[mr][reg] = fmaxf(fmaxf(sacc[mr][0][reg], sacc[mr][1][reg]),
                                    fmaxf(sacc[mr][2][reg], sacc[mr][3][reg]));
                need = need || (lm[mr][reg] > m_i[mr][reg]);
            }
        if (__any(need)) {
#pragma unroll
            for (int mr = 0; mr < 2; ++mr)
#pragma unroll
                for (int reg = 0; reg < 4; ++reg) {
                    float mt = lm[mr][reg];
                    mt = fmaxf(mt, __shfl_xor(mt, 1));
                    mt = fmaxf(mt, __shfl_xor(mt, 2));
                    mt = fmaxf(mt, __shfl_xor(mt, 4));
                    mt = fmaxf(mt, __shfl_xor(mt, 8));
                    const float mnew = fmaxf(m_i[mr][reg], mt + 3.0f);
                    const float rr = EXP2(m_i[mr][reg] - mnew);
                    m_i[mr][reg] = mnew;
                    lp[mr][reg] *= rr;
#pragma unroll
                    for (int df = 0; df < 4; ++df) O[mr][df][reg] *= rr;
                }
        }

        // p = exp2(s - m); per-lane partial l; route P through LDS
        _Float16* Pw = &Ps[wave][0];
#pragma unroll
        for (int mr = 0; mr < 2; ++mr)
#pragma unroll
            for (int reg = 0; reg < 4; ++reg) {
                const int row = mr * 16 + 4 * hi + reg;
                const float mi = m_i[mr][reg];
                float acc = 0.f;
#pragma unroll
                for (int cf = 0; cf < 4; ++cf) {
                    const float p = EXP2(sacc[mr][cf][reg] - mi);
                    acc += p;
                    Pw[row * 72 + cf * 16 + l15] = (_Float16)p;
                }
                lp[mr][reg] += acc;
            }

        // O += P V
        h8 pa[2][2];
#pragma unroll
        for (int mr = 0; mr < 2; ++mr)
#pragma unroll
            for (int ks = 0; ks < 2; ++ks)
                pa[mr][ks] = *(const h8*)&Pw[(mr * 16 + l15) * 72 + ks * 32 + hi * 8];
#pragma unroll
        for (int ks = 0; ks < 2; ++ks)
#pragma unroll
            for (int mr = 0; mr < 2; ++mr)
#pragma unroll
                for (int df = 0; df < 4; ++df)
                    O[mr][df] = __builtin_amdgcn_mfma_f32_16x16x32_f16(
                        pa[mr][ks], vb[ks][df], O[mr][df], 0, 0, 0);
    };

    // main loop: stage(t+1) issued before compute(t); one barrier per tile
    STAGE(0, 0);                 // tile 0 always kept (kl >= 1)
    __syncthreads();
    int buf = 0, k0 = 0, k1 = nxt(0);
    for (;;) {
        if (k1 >= 0) STAGE(buf ^ 1, k1);
        const bool wkeep = (k0 < kl) || (k0 <= qw + 31 + WIN && k0 + 63 >= qw - WIN);
        if (wkeep) TILE(buf, k0);
        __syncthreads();         // drains vmcnt(0): next tile staged; buf free
        if (k1 < 0) break;
        k0 = k1; k1 = nxt(k0); buf ^= 1;
    }

    // final l reduction across the 16 l15 lanes
    float lf[2][4];
#pragma unroll
    for (int mr = 0; mr < 2; ++mr)
#pragma unroll
        for (int reg = 0; reg < 4; ++reg) {
            float l = lp[mr][reg];
            l += __shfl_xor(l, 1); l += __shfl_xor(l, 2);
            l += __shfl_xor(l, 4); l += __shfl_xor(l, 8);
            lf[mr][reg] = l;
        }

    // epilogue -> Y fp16 (M, C) at row i*2+n, col h*64+d
#pragma unroll
    for (int mr = 0; mr < 2; ++mr)
#pragma unroll
        for (int reg = 0; reg < 4; ++reg) {
            const float inv = 1.f / lf[mr][reg];
            const int i = qw + mr * 16 + 4 * hi + reg;
#pragma unroll
            for (int df = 0; df < 4; ++df) {
                Y[((size_t)i * N_B + n) * C_DIM + h * DH + df * 16 + l15] =
                    (_Float16)(O[mr][df][reg] * inv);
            }
        }
}

extern "C" void kernel_launch(void* const* d_in, const int* in_sizes, int n_in,
                              void* d_out, int out_size, void* d_ws, size_t ws_size,
                              hipStream_t stream) {
    const float* q  = (const float*)d_in[0];
    const float* k  = (const float*)d_in[1];
    const float* v  = (const float*)d_in[2];
    const float* Wq = (const float*)d_in[3];
    const float* bq = (const float*)d_in[4];
    const float* Wk = (const float*)d_in[5];
    const float* bk = (const float*)d_in[6];
    const float* Wv = (const float*)d_in[7];
    const float* bv = (const float*)d_in[8];
    const float* Wo = (const float*)d_in[9];
    const float* bo = (const float*)d_in[10];
    const int*   kl = (const int*)d_in[11];

    const int NX = M_DIM * C_DIM;   // 4194304
    const int NW = C_DIM * C_DIM;   // 1048576

    _Float16* wq  = (_Float16*)d_ws;
    _Float16* wk  = wq + NW;
    _Float16* wv  = wk + NW;
    _Float16* wo  = wv + NW;
    _Float16* QHh = wo + NW;
    _Float16* KHh = QHh + NX;
    _Float16* VTh = KHh + NX;
    _Float16* Yh  = VTh + NX;

    Cvt4 c;
    c.a[0] = {Wq, wq}; c.a[1] = {Wk, wk}; c.a[2] = {Wv, wv}; c.a[3] = {Wo, wo};
    cvt_w<<<dim3(NW / (256 * 8), 4), 256, 0, stream>>>(c);

    QkvArgs qa;
    qa.x[0] = q;  qa.x[1] = k;  qa.x[2] = v;
    qa.w[0] = wq; qa.w[1] = wk; qa.w[2] = wv;
    qa.b[0] = bq; qa.b[1] = bk; qa.b[2] = bv;
    qa.out[0] = QHh; qa.out[1] = KHh; qa.out[2] = VTh;
    proj_qkv<<<dim3(M_DIM / 64, C_DIM / 128, 3), 256, 0, stream>>>(qa);

    attn_v7<<<dim3(N_B * H_DIM, T_DIM / 128), 256, 0, stream>>>(QHh, KHh, VTh, kl, Yh);

    proj_o<<<dim3(M_DIM / 64, C_DIM / 128), 256, 0, stream>>>(Yh, wo, bo, (float*)d_out);
}

// Round 17
// 100.347 us; speedup vs baseline: 1.1054x; 1.1054x over previous
//
#include <hip/hip_runtime.h>
#include <math.h>

#define T_DIM 2048
#define N_B   2
#define C_DIM 1024
#define H_DIM 16
#define DH    64
#define M_DIM 4096
#define WIN   128

typedef _Float16 h8 __attribute__((ext_vector_type(8)));
typedef float    f4 __attribute__((ext_vector_type(4)));

#if __has_builtin(__builtin_amdgcn_exp2f)
#define EXP2(x) __builtin_amdgcn_exp2f(x)
#else
#define EXP2(x) __expf((x) * 0.693147180559945f)
#endif

// ---------------------------------------------------------------------------
// async global->LDS, 16B per lane
// ---------------------------------------------------------------------------
__device__ __forceinline__ void glds16(const _Float16* g, _Float16* l) {
    typedef const __attribute__((address_space(1))) unsigned int guint;
    typedef __attribute__((address_space(3))) unsigned int luint;
    __builtin_amdgcn_global_load_lds((guint*)g, (luint*)l, 16, 0, 0);
}

__device__ __forceinline__ h8 cvt8(const float4 a, const float4 b) {
    h8 o;
    o[0] = (_Float16)a.x; o[1] = (_Float16)a.y;
    o[2] = (_Float16)a.z; o[3] = (_Float16)a.w;
    o[4] = (_Float16)b.x; o[5] = (_Float16)b.y;
    o[6] = (_Float16)b.z; o[7] = (_Float16)b.w;
    return o;
}

// ---------------------------------------------------------------------------
// fp32 -> fp16 conversion prepass (7 arrays; rounds 14-16 proved fusing this
// into the GEMM staging is net-neutral: reg-staging slows the loop by what
// the saved traffic buys)
// ---------------------------------------------------------------------------
struct CvtA { const float* s; _Float16* d; int n; };
struct Cvt7 { CvtA a[7]; };

__global__ __launch_bounds__(256) void cvt_k(Cvt7 c) {
    CvtA A = c.a[blockIdx.y];
    const int i = (blockIdx.x * 256 + threadIdx.x) * 8;
    if (i >= A.n) return;
    const float4 v0 = *(const float4*)&A.s[i];
    const float4 v1 = *(const float4*)&A.s[i + 4];
    *(h8*)&A.d[i] = cvt8(v0, v1);
}

// ---------------------------------------------------------------------------
// Projection GEMMs: 128x128 tile, BK=32, 4 waves (2x2 of 64x64), acc[4][4].
// Round-12-verified loop: 3-buf glds16 staging (swizzled source+read, 0 bank
// conflicts), counted s_waitcnt vmcnt(4) so the next stage's loads stay in
// flight across the barrier (fastest measured proj: 44.7 us).
// Round-13-style coalesced epilogue, adapted as TWO 32-row passes reusing
// the 48 KB staging LDS (per-wave-private scratch; DS ops in-order per wave).
// ---------------------------------------------------------------------------
struct QkvArgs {
    const _Float16* x[3];
    const _Float16* w[3];
    const float*    b[3];
    _Float16*       out[3];
};

__global__ __launch_bounds__(256) void proj_qkv(QkvArgs args) {
    const int z = blockIdx.z;
    const _Float16* __restrict__ A = args.x[z];
    const _Float16* __restrict__ B = args.w[z];
    const float* __restrict__ bias = args.b[z];
    _Float16* __restrict__ out     = args.out[z];

    __shared__ _Float16 Sm[3][8192];   // per buf: A 128x32 @0, B 128x32 @4096
    _Float16* smf = &Sm[0][0];

    const int tid  = threadIdx.x;
    const int lane = tid & 63;
    const int wave = tid >> 6;
    const int wr = wave >> 1, wc = wave & 1;
    const int l15 = lane & 15, hi = lane >> 4;
    const int m0 = blockIdx.x << 7;          // 128 rows
    const int o0 = blockIdx.y << 7;          // 128 cols

    auto STAGE = [&](int b, int k0) {        // 4 glds16 per thread
#pragma unroll
        for (int c = 0; c < 2; ++c) {
            const int chunk = tid + c * 256;             // 0..511
            const int row = chunk >> 2, c4 = chunk & 3;
            const int sc = (c4 ^ ((row >> 1) & 3)) << 3; // pre-swizzled src
            glds16(&A[(size_t)(m0 + row) * C_DIM + k0 + sc], &Sm[b][chunk << 3]);
        }
#pragma unroll
        for (int c = 0; c < 2; ++c) {
            const int chunk = tid + c * 256;
            const int row = chunk >> 2, c4 = chunk & 3;
            const int sc = (c4 ^ ((row >> 1) & 3)) << 3;
            glds16(&B[(size_t)(o0 + row) * C_DIM + k0 + sc],
                   &Sm[b][4096 + (chunk << 3)]);
        }
    };

    f4 acc[4][4];
    const f4 z4 = {0.f, 0.f, 0.f, 0.f};
#pragma unroll
    for (int i = 0; i < 4; ++i)
#pragma unroll
        for (int j = 0; j < 4; ++j) acc[i][j] = z4;

    STAGE(0, 0);
    STAGE(1, 32);
    int buf = 0;
    for (int k0 = 0; k0 < C_DIM; k0 += 32) {
        if (k0 + 32 < C_DIM) {
            asm volatile("s_waitcnt vmcnt(4)" ::: "memory");  // stage t done
        } else {
            asm volatile("s_waitcnt vmcnt(0)" ::: "memory");
        }
        __builtin_amdgcn_s_barrier();
        __builtin_amdgcn_sched_barrier(0);
        if (k0 + 64 < C_DIM) {
            const int nb = (buf + 2 >= 3) ? buf - 1 : buf + 2;
            STAGE(nb, k0 + 64);
        }

        h8 a[4], b[4];
#pragma unroll
        for (int mr = 0; mr < 4; ++mr) {
            const int R = wr * 64 + mr * 16 + l15;
            a[mr] = *(const h8*)&Sm[buf][R * 32 + ((hi ^ ((R >> 1) & 3)) << 3)];
        }
#pragma unroll
        for (int nf = 0; nf < 4; ++nf) {
            const int R = wc * 64 + nf * 16 + l15;
            b[nf] = *(const h8*)&Sm[buf][4096 + R * 32 + ((hi ^ ((R >> 1) & 3)) << 3)];
        }
#pragma unroll
        for (int mr = 0; mr < 4; ++mr)
#pragma unroll
            for (int nf = 0; nf < 4; ++nf)
                acc[mr][nf] = __builtin_amdgcn_mfma_f32_16x16x32_f16(
                    a[mr], b[nf], acc[mr][nf], 0, 0, 0);

        buf = (buf + 1 >= 3) ? 0 : buf + 1;
    }

    // -------- coalesced epilogue via LDS transpose scratch, 2 passes -------
    __syncthreads();
    const int hh = (o0 >> 6) + wc;
    if (z == 2) {
        // out (n,hh,d,t): per pass scratch [n*64+d][24], h8 stores of 8 t
        _Float16* ws = smf + wave * 3072;
#pragma unroll
        for (int pass = 0; pass < 2; ++pass) {
#pragma unroll
            for (int nf = 0; nf < 4; ++nf) {
                const float bb = bias[o0 + wc * 64 + nf * 16 + l15];
                const int d = nf * 16 + l15;
#pragma unroll
                for (int mr2 = 0; mr2 < 2; ++mr2)
#pragma unroll
                    for (int reg = 0; reg < 4; ++reg) {
                        const int ml = mr2 * 16 + 4 * hi + reg;
                        ws[((ml & 1) * 64 + d) * 24 + (ml >> 1)] =
                            (_Float16)(acc[pass * 2 + mr2][nf][reg] + bb);
                    }
            }
            const int tbase = (m0 + wr * 64 + pass * 32) >> 1;
#pragma unroll
            for (int it = 0; it < 4; ++it) {
                const int c = lane + it * 64;    // 0..255
                const int rowi = c >> 1;         // n*64+d
                const int th = (c & 1) << 3;
                const h8 v = *(const h8*)&ws[rowi * 24 + th];
                const int n = rowi >> 6, d = rowi & 63;
                *(h8*)&out[((size_t)((n * 16 + hh) * 64 + d)) * T_DIM + tbase + th] = v;
            }
        }
    } else {
        // out (n,hh,t,d): per pass scratch [ml 32][72]
        _Float16* ws = smf + wave * 2304;
#pragma unroll
        for (int pass = 0; pass < 2; ++pass) {
#pragma unroll
            for (int nf = 0; nf < 4; ++nf) {
                const float bb = bias[o0 + wc * 64 + nf * 16 + l15];
#pragma unroll
                for (int mr2 = 0; mr2 < 2; ++mr2)
#pragma unroll
                    for (int reg = 0; reg < 4; ++reg)
                        ws[(mr2 * 16 + 4 * hi + reg) * 72 + nf * 16 + l15] =
                            (_Float16)(acc[pass * 2 + mr2][nf][reg] + bb);
            }
            const int t0 = (m0 + wr * 64 + pass * 32) >> 1;
#pragma unroll
            for (int it = 0; it < 4; ++it) {
                const int c = lane + it * 64;    // 0..255
                const int nn = c >> 7;
                const int tq = (c >> 3) & 15;
                const int d8 = (c & 7) << 3;
                const int ml = (tq << 1) | nn;
                const h8 v = *(const h8*)&ws[ml * 72 + d8];
                *(h8*)&out[((size_t)(nn * 16 + hh) * T_DIM + t0 + tq) * DH + d8] = v;
            }
        }
    }
}

// ---------------------------------------------------------------------------
// Output projection: same 128x128 counted-vmcnt loop; fp32 float4 epilogue
// in 2 passes (scratch 4 waves x 32x68 floats = 34.8 KB <= 48 KB).
// ---------------------------------------------------------------------------
__global__ __launch_bounds__(256) void proj_o(
    const _Float16* __restrict__ A, const _Float16* __restrict__ B,
    const float* __restrict__ bias, float* __restrict__ out)
{
    __shared__ _Float16 Sm[3][8192];
    _Float16* smf = &Sm[0][0];

    const int tid  = threadIdx.x;
    const int lane = tid & 63;
    const int wave = tid >> 6;
    const int wr = wave >> 1, wc = wave & 1;
    const int l15 = lane & 15, hi = lane >> 4;
    const int m0 = blockIdx.x << 7;
    const int o0 = blockIdx.y << 7;

    auto STAGE = [&](int b, int k0) {
#pragma unroll
        for (int c = 0; c < 2; ++c) {
            const int chunk = tid + c * 256;
            const int row = chunk >> 2, c4 = chunk & 3;
            const int sc = (c4 ^ ((row >> 1) & 3)) << 3;
            glds16(&A[(size_t)(m0 + row) * C_DIM + k0 + sc], &Sm[b][chunk << 3]);
        }
#pragma unroll
        for (int c = 0; c < 2; ++c) {
            const int chunk = tid + c * 256;
            const int row = chunk >> 2, c4 = chunk & 3;
            const int sc = (c4 ^ ((row >> 1) & 3)) << 3;
            glds16(&B[(size_t)(o0 + row) * C_DIM + k0 + sc],
                   &Sm[b][4096 + (chunk << 3)]);
        }
    };

    f4 acc[4][4];
    const f4 z4 = {0.f, 0.f, 0.f, 0.f};
#pragma unroll
    for (int i = 0; i < 4; ++i)
#pragma unroll
        for (int j = 0; j < 4; ++j) acc[i][j] = z4;

    STAGE(0, 0);
    STAGE(1, 32);
    int buf = 0;
    for (int k0 = 0; k0 < C_DIM; k0 += 32) {
        if (k0 + 32 < C_DIM) {
            asm volatile("s_waitcnt vmcnt(4)" ::: "memory");
        } else {
            asm volatile("s_waitcnt vmcnt(0)" ::: "memory");
        }
        __builtin_amdgcn_s_barrier();
        __builtin_amdgcn_sched_barrier(0);
        if (k0 + 64 < C_DIM) {
            const int nb = (buf + 2 >= 3) ? buf - 1 : buf + 2;
            STAGE(nb, k0 + 64);
        }

        h8 a[4], b[4];
#pragma unroll
        for (int mr = 0; mr < 4; ++mr) {
            const int R = wr * 64 + mr * 16 + l15;
            a[mr] = *(const h8*)&Sm[buf][R * 32 + ((hi ^ ((R >> 1) & 3)) << 3)];
        }
#pragma unroll
        for (int nf = 0; nf < 4; ++nf) {
            const int R = wc * 64 + nf * 16 + l15;
            b[nf] = *(const h8*)&Sm[buf][4096 + R * 32 + ((hi ^ ((R >> 1) & 3)) << 3)];
        }
#pragma unroll
        for (int mr = 0; mr < 4; ++mr)
#pragma unroll
            for (int nf = 0; nf < 4; ++nf)
                acc[mr][nf] = __builtin_amdgcn_mfma_f32_16x16x32_f16(
                    a[mr], b[nf], acc[mr][nf], 0, 0, 0);

        buf = (buf + 1 >= 3) ? 0 : buf + 1;
    }

    // coalesced fp32 epilogue, 2 passes: scratch [ml 32][68] floats
    __syncthreads();
    float* wsf = (float*)smf + wave * 2176;
#pragma unroll
    for (int pass = 0; pass < 2; ++pass) {
#pragma unroll
        for (int nf = 0; nf < 4; ++nf) {
            const float bb = bias[o0 + wc * 64 + nf * 16 + l15];
#pragma unroll
            for (int mr2 = 0; mr2 < 2; ++mr2)
#pragma unroll
                for (int reg = 0; reg < 4; ++reg)
                    wsf[(mr2 * 16 + 4 * hi + reg) * 68 + nf * 16 + l15] =
                        acc[pass * 2 + mr2][nf][reg] + bb;
        }
        const int rbase = m0 + wr * 64 + pass * 32;
#pragma unroll
        for (int it = 0; it < 8; ++it) {
            const int c = lane + it * 64;        // 0..511
            const int ml = c >> 4;
            const int o4 = (c & 15) << 2;
            const f4 v = *(const f4*)&wsf[ml * 68 + o4];
            *(f4*)&out[(size_t)(rbase + ml) * C_DIM + o0 + wc * 64 + o4] = v;
        }
    }
}

// ---------------------------------------------------------------------------
// Flash attention v7 (unchanged): 4-wave blocks, 128 q-rows, LDS-staged
// swizzled K/V^T, double-buffered, kept-tile walker, defer-max.
// ---------------------------------------------------------------------------
__global__ __launch_bounds__(256, 2) void attn_v7(
    const _Float16* __restrict__ QH, const _Float16* __restrict__ KH,
    const _Float16* __restrict__ VT, const int* __restrict__ key_length,
    _Float16* __restrict__ Y)
{
    __shared__ _Float16 Ks[2][64 * 64];     // [key][d], swizzled
    __shared__ _Float16 Vs[2][64 * 64];     // [d][key], swizzled
    __shared__ _Float16 Ps[4][32 * 72];     // per-wave P routing

    const int nh = blockIdx.x;
    const int n  = nh >> 4;
    const int h  = nh & 15;
    const int qb = blockIdx.y << 7;          // 128 q-rows per block
    const int kl = key_length[n];
    const int tid  = threadIdx.x;
    const int wave = tid >> 6;
    const int lane = tid & 63;
    const int l15 = lane & 15, hi = lane >> 4;
    const int qw = qb + wave * 32;           // this wave's 32 rows
    const int swz = l15 & 7;                 // read-side XOR key

    const size_t hb = (size_t)nh * T_DIM * DH;
    const _Float16* Qb = QH + hb;
    const _Float16* Kb = KH + hb;
    const _Float16* Vb = VT + hb;            // [d][t] within this head

    // block-level kept-tile walker: prefix [0,klc) union band [blo,bhi]
    const int klc0 = ((kl + 63) >> 6) << 6;
    const int klc  = (klc0 < T_DIM) ? klc0 : T_DIM;
    const int blo  = (qb >= WIN) ? ((qb - WIN) & ~63) : 0;
    int bhi = ((qb + 127 + WIN) >> 6) << 6;
    if (bhi > T_DIM - 64) bhi = T_DIM - 64;
    auto nxt = [&](int k0) -> int {
        k0 += 64;
        if (k0 < klc) return k0;
        if (k0 < blo) k0 = blo;
        return (k0 <= bhi) ? k0 : -1;
    };

    auto STAGE = [&](int b, int k0) {
#pragma unroll
        for (int c = 0; c < 2; ++c) {
            const int slot = wave * 128 + c * 64 + lane;   // 16B slot in tile
            const int r = slot >> 3, c16 = slot & 7;
            const int sc = (c16 ^ (r & 7)) << 3;           // element offset
            glds16(&Kb[(size_t)(k0 + r) * DH + sc], &Ks[b][slot << 3]);
        }
#pragma unroll
        for (int c = 0; c < 2; ++c) {
            const int slot = wave * 128 + c * 64 + lane;
            const int r = slot >> 3, c16 = slot & 7;
            const int sc = (c16 ^ (r & 7)) << 3;
            glds16(&Vb[(size_t)r * T_DIM + k0 + sc], &Vs[b][slot << 3]);
        }
    };

    // Q A-fragments
    h8 qa[2][2];
#pragma unroll
    for (int mr = 0; mr < 2; ++mr)
#pragma unroll
        for (int ks = 0; ks < 2; ++ks)
            qa[mr][ks] = *(const h8*)&Qb[(size_t)(qw + mr * 16 + l15) * DH + ks * 32 + hi * 8];

    f4 O[2][4];
    const f4 z4 = {0.f, 0.f, 0.f, 0.f};
#pragma unroll
    for (int mr = 0; mr < 2; ++mr)
#pragma unroll
        for (int df = 0; df < 4; ++df) O[mr][df] = z4;
    float m_i[2][4], lp[2][4];
#pragma unroll
    for (int mr = 0; mr < 2; ++mr)
#pragma unroll
        for (int r = 0; r < 4; ++r) { m_i[mr][r] = -1e30f; lp[mr][r] = 0.f; }

    const float SC = 0.18033688f;            // (1/sqrt(64)) * log2(e)

    auto TILE = [&](int b, int k0) {
        // K fragments from swizzled LDS
        h8 kb[2][4];
#pragma unroll
        for (int ks = 0; ks < 2; ++ks)
#pragma unroll
            for (int cf = 0; cf < 4; ++cf)
                kb[ks][cf] = *(const h8*)&Ks[b][(cf * 16 + l15) * 64 +
                                                (((ks * 4 + hi) ^ swz) << 3)];

        // S = Q K^T
        f4 sacc[2][4];
#pragma unroll
        for (int mr = 0; mr < 2; ++mr)
#pragma unroll
            for (int cf = 0; cf < 4; ++cf) sacc[mr][cf] = z4;
#pragma unroll
        for (int ks = 0; ks < 2; ++ks)
#pragma unroll
            for (int mr = 0; mr < 2; ++mr)
#pragma unroll
                for (int cf = 0; cf < 4; ++cf)
                    sacc[mr][cf] = __builtin_amdgcn_mfma_f32_16x16x32_f16(
                        qa[mr][ks], kb[ks][cf], sacc[mr][cf], 0, 0, 0);

        // V fragments issued now; LDS latency hides under softmax
        h8 vb[2][4];
#pragma unroll
        for (int ks = 0; ks < 2; ++ks)
#pragma unroll
            for (int df = 0; df < 4; ++df)
                vb[ks][df] = *(const h8*)&Vs[b][(df * 16 + l15) * 64 +
                                                (((ks * 4 + hi) ^ swz) << 3)];

        const bool full = (k0 + 63 < kl) ||
                          (k0 >= qw + 31 - WIN && k0 + 63 <= qw + WIN);

        // scale + mask in place
#pragma unroll
        for (int mr = 0; mr < 2; ++mr) {
            if (full) {
#pragma unroll
                for (int cf = 0; cf < 4; ++cf)
#pragma unroll
                    for (int reg = 0; reg < 4; ++reg)
                        sacc[mr][cf][reg] *= SC;
            } else {
#pragma unroll
                for (int cf = 0; cf < 4; ++cf)
#pragma unroll
                    for (int reg = 0; reg < 4; ++reg) {
                        const int i = qw + mr * 16 + 4 * hi + reg;
                        const int j = k0 + cf * 16 + l15;
                        const int dd = i - j;
                        const bool ok = (dd <= WIN && dd >= -WIN) || (j < kl);
                        sacc[mr][cf][reg] = ok ? sacc[mr][cf][reg] * SC : -1e9f;
                    }
            }
        }

        // defer-max: reduce + rescale only when some lane exceeds m_i
        float lm[2][4];
        bool need = false;
#pragma unroll
        for (int mr = 0; mr < 2; ++mr)
#pragma unroll
            for (int reg = 0; reg < 4; ++reg) {
                lm[mr][reg] = fmaxf(fmaxf(sacc[mr][0][reg], sacc[mr][1][reg]),
                                    fmaxf(sacc[mr][2][reg], sacc[mr][3][reg]));
                need = need || (lm[mr][reg] > m_i[mr][reg]);
            }
        if (__any(need)) {
#pragma unroll
            for (int mr = 0; mr < 2; ++mr)
#pragma unroll
                for (int reg = 0; reg < 4; ++reg) {
                    float mt = lm[mr][reg];
                    mt = fmaxf(mt, __shfl_xor(mt, 1));
                    mt = fmaxf(mt, __shfl_xor(mt, 2));
                    mt = fmaxf(mt, __shfl_xor(mt, 4));
                    mt = fmaxf(mt, __shfl_xor(mt, 8));
                    const float mnew = fmaxf(m_i[mr][reg], mt + 3.0f);
                    const float rr = EXP2(m_i[mr][reg] - mnew);
                    m_i[mr][reg] = mnew;
                    lp[mr][reg] *= rr;
#pragma unroll
                    for (int df = 0; df < 4; ++df) O[mr][df][reg] *= rr;
                }
        }

        // p = exp2(s - m); per-lane partial l; route P through LDS
        _Float16* Pw = &Ps[wave][0];
#pragma unroll
        for (int mr = 0; mr < 2; ++mr)
#pragma unroll
            for (int reg = 0; reg < 4; ++reg) {
                const int row = mr * 16 + 4 * hi + reg;
                const float mi = m_i[mr][reg];
                float acc = 0.f;
#pragma unroll
                for (int cf = 0; cf < 4; ++cf) {
                    const float p = EXP2(sacc[mr][cf][reg] - mi);
                    acc += p;
                    Pw[row * 72 + cf * 16 + l15] = (_Float16)p;
                }
                lp[mr][reg] += acc;
            }

        // O += P V
        h8 pa[2][2];
#pragma unroll
        for (int mr = 0; mr < 2; ++mr)
#pragma unroll
            for (int ks = 0; ks < 2; ++ks)
                pa[mr][ks] = *(const h8*)&Pw[(mr * 16 + l15) * 72 + ks * 32 + hi * 8];
#pragma unroll
        for (int ks = 0; ks < 2; ++ks)
#pragma unroll
            for (int mr = 0; mr < 2; ++mr)
#pragma unroll
                for (int df = 0; df < 4; ++df)
                    O[mr][df] = __builtin_amdgcn_mfma_f32_16x16x32_f16(
                        pa[mr][ks], vb[ks][df], O[mr][df], 0, 0, 0);
    };

    // main loop: stage(t+1) issued before compute(t); one barrier per tile
    STAGE(0, 0);                 // tile 0 always kept (kl >= 1)
    __syncthreads();
    int buf = 0, k0 = 0, k1 = nxt(0);
    for (;;) {
        if (k1 >= 0) STAGE(buf ^ 1, k1);
        const bool wkeep = (k0 < kl) || (k0 <= qw + 31 + WIN && k0 + 63 >= qw - WIN);
        if (wkeep) TILE(buf, k0);
        __syncthreads();         // drains vmcnt(0): next tile staged; buf free
        if (k1 < 0) break;
        k0 = k1; k1 = nxt(k0); buf ^= 1;
    }

    // final l reduction across the 16 l15 lanes
    float lf[2][4];
#pragma unroll
    for (int mr = 0; mr < 2; ++mr)
#pragma unroll
        for (int reg = 0; reg < 4; ++reg) {
            float l = lp[mr][reg];
            l += __shfl_xor(l, 1); l += __shfl_xor(l, 2);
            l += __shfl_xor(l, 4); l += __shfl_xor(l, 8);
            lf[mr][reg] = l;
        }

    // epilogue -> Y fp16 (M, C) at row i*2+n, col h*64+d
#pragma unroll
    for (int mr = 0; mr < 2; ++mr)
#pragma unroll
        for (int reg = 0; reg < 4; ++reg) {
            const float inv = 1.f / lf[mr][reg];
            const int i = qw + mr * 16 + 4 * hi + reg;
#pragma unroll
            for (int df = 0; df < 4; ++df) {
                Y[((size_t)i * N_B + n) * C_DIM + h * DH + df * 16 + l15] =
                    (_Float16)(O[mr][df][reg] * inv);
            }
        }
}

extern "C" void kernel_launch(void* const* d_in, const int* in_sizes, int n_in,
                              void* d_out, int out_size, void* d_ws, size_t ws_size,
                              hipStream_t stream) {
    const float* q  = (const float*)d_in[0];
    const float* k  = (const float*)d_in[1];
    const float* v  = (const float*)d_in[2];
    const float* Wq = (const float*)d_in[3];
    const float* bq = (const float*)d_in[4];
    const float* Wk = (const float*)d_in[5];
    const float* bk = (const float*)d_in[6];
    const float* Wv = (const float*)d_in[7];
    const float* bv = (const float*)d_in[8];
    const float* Wo = (const float*)d_in[9];
    const float* bo = (const float*)d_in[10];
    const int*   kl = (const int*)d_in[11];

    const int NX = M_DIM * C_DIM;   // 4194304
    const int NW = C_DIM * C_DIM;   // 1048576

    _Float16* xq = (_Float16*)d_ws;
    _Float16* xk = xq + NX;
    _Float16* xv = xk + NX;
    _Float16* wq = xv + NX;
    _Float16* wk = wq + NW;
    _Float16* wv = wk + NW;
    _Float16* wo = wv + NW;
    _Float16* QHh = wo + NW;
    _Float16* KHh = QHh + NX;
    _Float16* VTh = KHh + NX;
    _Float16* Yh  = xq;             // reuse xq after projections

    Cvt7 c;
    c.a[0] = {q,  xq, NX}; c.a[1] = {k,  xk, NX}; c.a[2] = {v,  xv, NX};
    c.a[3] = {Wq, wq, NW}; c.a[4] = {Wk, wk, NW};
    c.a[5] = {Wv, wv, NW}; c.a[6] = {Wo, wo, NW};
    cvt_k<<<dim3(NX / (256 * 8), 7), 256, 0, stream>>>(c);

    QkvArgs qa;
    qa.x[0] = xq; qa.x[1] = xk; qa.x[2] = xv;
    qa.w[0] = wq; qa.w[1] = wk; qa.w[2] = wv;
    qa.b[0] = bq; qa.b[1] = bk; qa.b[2] = bv;
    qa.out[0] = QHh; qa.out[1] = KHh; qa.out[2] = VTh;
    proj_qkv<<<dim3(M_DIM / 128, C_DIM / 128, 3), 256, 0, stream>>>(qa);

    attn_v7<<<dim3(N_B * H_DIM, T_DIM / 128), 256, 0, stream>>>(QHh, KHh, VTh, kl, Yh);

    proj_o<<<dim3(M_DIM / 128, C_DIM / 128), 256, 0, stream>>>(Yh, wo, bo, (float*)d_out);
}